// Round 4
// baseline (185.619 us; speedup 1.0000x reference)
//
#include <hip/hip_runtime.h>

// GraphSage on MI355X — round 4.
//   prep  : feat fp32 [N,128] -> fb bf16 (GEMM self operand) + f8 fp8 e4m3 (gather source)
//           + w1,w2 fp32 [256,128] -> w1T,w2T bf16 [n][k]
//   k1_agg: standalone high-occupancy gather: agg[N,128] bf16 = mean_d f8[nbr[n][d]]
//   g1    : h1[N,128] bf16 = [fb | agg] @ w1T  — B held in VGPRs (each wave owns a
//           32-col slice; w1T read exactly once per block), A streamed 32 rows/chunk,
//           no LDS, no barriers. Fixes round-3's register-starved latency-bound loop
//           (VGPR was 88 with 64 acc regs -> serialized B loads).
//   g2    : out[B,128] fp32 = [h1[node] | mean h1[nbr]] @ w2T  (fused, 64 rows/block)

#define N_NODES 100000
#define DEG     16
#define FDIM    128
#define HDIM    128
#define B_NODES 8192

typedef __attribute__((ext_vector_type(8))) short bf16x8;
typedef __attribute__((ext_vector_type(8))) unsigned short u16x8;
typedef __attribute__((ext_vector_type(4))) float f32x4;
typedef __attribute__((ext_vector_type(2))) float f32x2;

static __device__ __forceinline__ unsigned short f2bf(float f) {
    union { float f; unsigned u; } v; v.f = f;
    unsigned r = v.u + 0x7fff + ((v.u >> 16) & 1);   // RNE
    return (unsigned short)(r >> 16);
}
static __device__ __forceinline__ float bf2f(unsigned short b) {
    union { unsigned u; float f; } v; v.u = ((unsigned)b) << 16;
    return v.f;
}

// blocks 0..6249: cast feat -> fb (bf16) + f8 (fp8). blocks 6250..6265: w1/w2 transpose.
__global__ __launch_bounds__(256)
void prep(const float* __restrict__ feat, const float* __restrict__ w1,
          const float* __restrict__ w2, unsigned short* __restrict__ fb,
          unsigned char* __restrict__ f8,
          unsigned short* __restrict__ w1T, unsigned short* __restrict__ w2T) {
    if (blockIdx.x < 6250) {
        long e = ((long)blockIdx.x * 256 + threadIdx.x) * 8;   // 6250*256*8 = 12.8M exact
        float4 v0 = *(const float4*)(feat + e);
        float4 v1 = *(const float4*)(feat + e + 4);
        u16x8 ob;
        ob[0] = f2bf(v0.x); ob[1] = f2bf(v0.y); ob[2] = f2bf(v0.z); ob[3] = f2bf(v0.w);
        ob[4] = f2bf(v1.x); ob[5] = f2bf(v1.y); ob[6] = f2bf(v1.z); ob[7] = f2bf(v1.w);
        *(u16x8*)(fb + e) = ob;
        int p0 = 0, p1 = 0;
        p0 = __builtin_amdgcn_cvt_pk_fp8_f32(v0.x, v0.y, p0, false);
        p0 = __builtin_amdgcn_cvt_pk_fp8_f32(v0.z, v0.w, p0, true);
        p1 = __builtin_amdgcn_cvt_pk_fp8_f32(v1.x, v1.y, p1, false);
        p1 = __builtin_amdgcn_cvt_pk_fp8_f32(v1.z, v1.w, p1, true);
        uint2 o8; o8.x = (unsigned)p0; o8.y = (unsigned)p1;
        *(uint2*)(f8 + e) = o8;
    } else {
        int bid = blockIdx.x - 6250;
        const float* w = (bid < 8) ? w1 : w2;
        unsigned short* wT = (bid < 8) ? w1T : w2T;
        int kb = (bid & 7) * 32;
        int n = threadIdx.x & 127, dk = threadIdx.x >> 7;
#pragma unroll
        for (int i = 0; i < 16; ++i) {
            int k = kb + dk * 16 + i;
            wT[n * 256 + k] = f2bf(w[k * 128 + n]);   // read coalesced over n
        }
    }
}

// 16 nodes per 256-thread block; 16 lanes per node, 8 B fp8 per lane per neighbor.
// Fabric/L2-miss bound (~4 TB/s); high occupancy (VGPR 20) is the point.
__global__ __launch_bounds__(256)
void k1_agg(const unsigned char* __restrict__ f8, const int* __restrict__ nbr,
            unsigned short* __restrict__ agg) {
    const int t = threadIdx.x;
    const int node = blockIdx.x * 16 + (t >> 4);      // 6250*16 = 100000 exact
    const int cg = (t & 15) * 8;
    const int* idx = nbr + node * DEG;
    float s[8] = {0.f, 0.f, 0.f, 0.f, 0.f, 0.f, 0.f, 0.f};
#pragma unroll
    for (int d = 0; d < DEG; ++d) {
        int nb = idx[d];
        uint2 v = *(const uint2*)(f8 + (long)nb * FDIM + cg);
        f32x2 a0 = __builtin_amdgcn_cvt_pk_f32_fp8((int)v.x, false);
        f32x2 a1 = __builtin_amdgcn_cvt_pk_f32_fp8((int)v.x, true);
        f32x2 a2 = __builtin_amdgcn_cvt_pk_f32_fp8((int)v.y, false);
        f32x2 a3 = __builtin_amdgcn_cvt_pk_f32_fp8((int)v.y, true);
        s[0] += a0[0]; s[1] += a0[1]; s[2] += a1[0]; s[3] += a1[1];
        s[4] += a2[0]; s[5] += a2[1]; s[6] += a3[0]; s[7] += a3[1];
    }
    u16x8 o;
#pragma unroll
    for (int j = 0; j < 8; ++j) o[j] = f2bf(s[j] * 0.0625f);
    *(u16x8*)(agg + node * 128 + cg) = o;
}

// GEMM: h1 = [fb | agg] @ w1T. 128 rows/block. Each wave: 32-col slice, B in VGPRs.
__global__ __launch_bounds__(256, 3)
void g1(const unsigned short* __restrict__ fb, const unsigned short* __restrict__ agg,
        const unsigned short* __restrict__ w1T, unsigned short* __restrict__ h1) {
    const int t = threadIdx.x, wave = t >> 6, lane = t & 63;
    const int m16 = lane & 15, quad = lane >> 4;
    const int row0 = blockIdx.x * 128;
    const int n0 = wave * 32;

    // B preload: this wave's 32 cols x 256 k. 16 frags = 64 VGPRs.
    // Waves load disjoint slices -> block reads w1T exactly once (64 KB).
    bf16x8 B[8][2];
#pragma unroll
    for (int kc = 0; kc < 8; ++kc)
#pragma unroll
        for (int nt = 0; nt < 2; ++nt)
            B[kc][nt] = *(const bf16x8*)(w1T + (n0 + nt * 16 + m16) * 256 + kc * 32 + quad * 8);

    for (int c = 0; c < 4; ++c) {
        const int r0 = row0 + c * 32;
        // All 16 A loads issued up front (independent).
        bf16x8 A[2][8];
#pragma unroll
        for (int mt = 0; mt < 2; ++mt) {
            int grow = r0 + mt * 16 + m16;
            bool ok = grow < N_NODES;
            const unsigned short* pf = fb + (long)grow * 128 + quad * 8;
            const unsigned short* pa = agg + (long)grow * 128 + quad * 8;
            bf16x8 z = {};
#pragma unroll
            for (int kc = 0; kc < 4; ++kc)
                A[mt][kc] = ok ? *(const bf16x8*)(pf + kc * 32) : z;
#pragma unroll
            for (int kc = 4; kc < 8; ++kc)
                A[mt][kc] = ok ? *(const bf16x8*)(pa + (kc - 4) * 32) : z;
        }

        f32x4 acc[2][2] = {};
#pragma unroll
        for (int kc = 0; kc < 8; ++kc)
#pragma unroll
            for (int mt = 0; mt < 2; ++mt)
#pragma unroll
                for (int nt = 0; nt < 2; ++nt)
                    acc[mt][nt] = __builtin_amdgcn_mfma_f32_16x16x32_bf16(A[mt][kc], B[kc][nt], acc[mt][nt], 0, 0, 0);

        // C layout: row = quad*4 + reg, col = nt*16 + m16 (within this wave's slice)
#pragma unroll
        for (int mt = 0; mt < 2; ++mt)
#pragma unroll
            for (int reg = 0; reg < 4; ++reg) {
                int grow = r0 + mt * 16 + quad * 4 + reg;
                if (grow >= N_NODES) continue;
#pragma unroll
                for (int nt = 0; nt < 2; ++nt)
                    h1[grow * HDIM + n0 + nt * 16 + m16] = f2bf(acc[mt][nt][reg]);
            }
    }
}

// Layer 2 fused: 64 batch rows per 256-thread block. 128 blocks exact.
__global__ __launch_bounds__(256)
void g2_fused(const unsigned short* __restrict__ h1, const unsigned short* __restrict__ w2T,
              const int* __restrict__ nbr, const int* __restrict__ nodes,
              float* __restrict__ out) {
    __shared__ unsigned short X2[64][264];
    const int t = threadIdx.x, wave = t >> 6, lane = t & 63;
    const int m16 = lane & 15, quad = lane >> 4;
    const int b0 = blockIdx.x * 64;
    const int colb = m16 * 8;

    for (int g = 0; g < 4; ++g) {
        int Ln = wave * 16 + g * 4 + quad;
        int node = nodes[b0 + Ln];
        *(u16x8*)(&X2[Ln][colb]) = *(const u16x8*)(h1 + node * HDIM + colb);
        const int* idx = nbr + node * DEG;
        float s[8] = {0.f, 0.f, 0.f, 0.f, 0.f, 0.f, 0.f, 0.f};
#pragma unroll
        for (int d = 0; d < DEG; ++d) {
            int nb = idx[d];
            u16x8 v = *(const u16x8*)(h1 + nb * HDIM + colb);
#pragma unroll
            for (int j = 0; j < 8; ++j) s[j] += bf2f(v[j]);
        }
        u16x8 o;
#pragma unroll
        for (int j = 0; j < 8; ++j) o[j] = f2bf(s[j] * 0.0625f);
        *(u16x8*)(&X2[Ln][128 + colb]) = o;
    }
    __syncthreads();

    f32x4 acc[8] = {};
#pragma unroll
    for (int kc = 0; kc < 8; ++kc) {
        bf16x8 a = *(const bf16x8*)(&X2[wave * 16 + m16][kc * 32 + quad * 8]);
#pragma unroll
        for (int nt = 0; nt < 8; ++nt) {
            bf16x8 b = *(const bf16x8*)(w2T + (nt * 16 + m16) * 256 + kc * 32 + quad * 8);
            acc[nt] = __builtin_amdgcn_mfma_f32_16x16x32_bf16(a, b, acc[nt], 0, 0, 0);
        }
    }

#pragma unroll
    for (int nt = 0; nt < 8; ++nt)
#pragma unroll
        for (int reg = 0; reg < 4; ++reg) {
            int row = b0 + wave * 16 + quad * 4 + reg;
            out[row * 128 + nt * 16 + m16] = acc[nt][reg];
        }
}

extern "C" void kernel_launch(void* const* d_in, const int* in_sizes, int n_in,
                              void* d_out, int out_size, void* d_ws, size_t ws_size,
                              hipStream_t stream) {
    const float* feat  = (const float*)d_in[0];
    const float* w1    = (const float*)d_in[1];
    const float* w2    = (const float*)d_in[2];
    const int*   nbr   = (const int*)d_in[3];
    const int*   nodes = (const int*)d_in[4];
    float* out = (float*)d_out;

    char* ws = (char*)d_ws;
    unsigned short* fb  = (unsigned short*)ws;                       // N*128 bf16 = 25.6 MB
    unsigned char*  f8  = (unsigned char*)(ws + 25600000);           // N*128 fp8  = 12.8 MB
    unsigned short* agg = (unsigned short*)(ws + 38400000);          // N*128 bf16 = 25.6 MB
    unsigned short* h1  = (unsigned short*)(ws + 64000000);          // N*128 bf16 = 25.6 MB
    unsigned short* w1T = (unsigned short*)(ws + 89600000);          // 64 KB
    unsigned short* w2T = (unsigned short*)(ws + 89665536);          // 64 KB

    prep<<<6266, 256, 0, stream>>>(feat, w1, w2, fb, f8, w1T, w2T);
    k1_agg<<<6250, 256, 0, stream>>>(f8, nbr, agg);
    g1<<<(N_NODES + 127) / 128, 256, 0, stream>>>(fb, agg, w1T, h1);
    g2_fused<<<B_NODES / 64, 256, 0, stream>>>(h1, w2T, nbr, nodes, out);
}

// Round 5
// 182.524 us; speedup vs baseline: 1.0170x; 1.0170x over previous
//
#include <hip/hip_runtime.h>

// GraphSage on MI355X — round 5.
//   prep  : feat fp32 [N,128] -> fb bf16 (GEMM self operand) + f8 fp8 e4m3 (gather source)
//           + w1,w2 fp32 [256,128] -> w1T,w2T bf16 [n][k]
//   k1_agg: standalone high-occupancy gather: agg[N,128] bf16 = mean_d f8[nbr[n][d]]
//           (fabric/L3-bound ~3.5 TB/s; VGPR 20 -> max waves)
//   g1    : h1[N,128] bf16 = [fb | agg] @ w1T.  w1T staged in LDS (64 KB, stride 264
//           -> uniform bank spread), A ping-pong prefetched from global. Fixes round-4's
//           register-starved B (VGPR 76 < needed -> B reloaded every chunk, latency-bound).
//   g2    : out[B,128] fp32 = [h1[node] | mean h1[nbr]] @ w2T  (fused, 64 rows/block)

#define N_NODES 100000
#define DEG     16
#define FDIM    128
#define HDIM    128
#define B_NODES 8192

typedef __attribute__((ext_vector_type(8))) short bf16x8;
typedef __attribute__((ext_vector_type(8))) unsigned short u16x8;
typedef __attribute__((ext_vector_type(4))) float f32x4;
typedef __attribute__((ext_vector_type(2))) float f32x2;

static __device__ __forceinline__ unsigned short f2bf(float f) {
    union { float f; unsigned u; } v; v.f = f;
    unsigned r = v.u + 0x7fff + ((v.u >> 16) & 1);   // RNE
    return (unsigned short)(r >> 16);
}
static __device__ __forceinline__ float bf2f(unsigned short b) {
    union { unsigned u; float f; } v; v.u = ((unsigned)b) << 16;
    return v.f;
}

// blocks 0..6249: cast feat -> fb (bf16) + f8 (fp8). blocks 6250..6265: w1/w2 transpose.
__global__ __launch_bounds__(256)
void prep(const float* __restrict__ feat, const float* __restrict__ w1,
          const float* __restrict__ w2, unsigned short* __restrict__ fb,
          unsigned char* __restrict__ f8,
          unsigned short* __restrict__ w1T, unsigned short* __restrict__ w2T) {
    if (blockIdx.x < 6250) {
        long e = ((long)blockIdx.x * 256 + threadIdx.x) * 8;   // 6250*256*8 = 12.8M exact
        float4 v0 = *(const float4*)(feat + e);
        float4 v1 = *(const float4*)(feat + e + 4);
        u16x8 ob;
        ob[0] = f2bf(v0.x); ob[1] = f2bf(v0.y); ob[2] = f2bf(v0.z); ob[3] = f2bf(v0.w);
        ob[4] = f2bf(v1.x); ob[5] = f2bf(v1.y); ob[6] = f2bf(v1.z); ob[7] = f2bf(v1.w);
        *(u16x8*)(fb + e) = ob;
        int p0 = 0, p1 = 0;
        p0 = __builtin_amdgcn_cvt_pk_fp8_f32(v0.x, v0.y, p0, false);
        p0 = __builtin_amdgcn_cvt_pk_fp8_f32(v0.z, v0.w, p0, true);
        p1 = __builtin_amdgcn_cvt_pk_fp8_f32(v1.x, v1.y, p1, false);
        p1 = __builtin_amdgcn_cvt_pk_fp8_f32(v1.z, v1.w, p1, true);
        uint2 o8; o8.x = (unsigned)p0; o8.y = (unsigned)p1;
        *(uint2*)(f8 + e) = o8;
    } else {
        int bid = blockIdx.x - 6250;
        const float* w = (bid < 8) ? w1 : w2;
        unsigned short* wT = (bid < 8) ? w1T : w2T;
        int kb = (bid & 7) * 32;
        int n = threadIdx.x & 127, dk = threadIdx.x >> 7;
#pragma unroll
        for (int i = 0; i < 16; ++i) {
            int k = kb + dk * 16 + i;
            wT[n * 256 + k] = f2bf(w[k * 128 + n]);   // read coalesced over n
        }
    }
}

// 16 nodes per 256-thread block; 16 lanes per node, 8 B fp8 per lane per neighbor.
__global__ __launch_bounds__(256)
void k1_agg(const unsigned char* __restrict__ f8, const int* __restrict__ nbr,
            unsigned short* __restrict__ agg) {
    const int t = threadIdx.x;
    const int node = blockIdx.x * 16 + (t >> 4);      // 6250*16 = 100000 exact
    const int cg = (t & 15) * 8;
    const int* idx = nbr + node * DEG;
    float s[8] = {0.f, 0.f, 0.f, 0.f, 0.f, 0.f, 0.f, 0.f};
#pragma unroll
    for (int d = 0; d < DEG; ++d) {
        int nb = idx[d];
        uint2 v = *(const uint2*)(f8 + (long)nb * FDIM + cg);
        f32x2 a0 = __builtin_amdgcn_cvt_pk_f32_fp8((int)v.x, false);
        f32x2 a1 = __builtin_amdgcn_cvt_pk_f32_fp8((int)v.x, true);
        f32x2 a2 = __builtin_amdgcn_cvt_pk_f32_fp8((int)v.y, false);
        f32x2 a3 = __builtin_amdgcn_cvt_pk_f32_fp8((int)v.y, true);
        s[0] += a0[0]; s[1] += a0[1]; s[2] += a1[0]; s[3] += a1[1];
        s[4] += a2[0]; s[5] += a2[1]; s[6] += a3[0]; s[7] += a3[1];
    }
    u16x8 o;
#pragma unroll
    for (int j = 0; j < 8; ++j) o[j] = f2bf(s[j] * 0.0625f);
    *(u16x8*)(agg + node * 128 + cg) = o;
}

// GEMM: h1 = [fb | agg] @ w1T. 128 rows x 128 cols per block; 4 waves, each a 32-col slice.
// B from LDS (staged once), A ping-pong prefetched 32 rows at a time.
__global__ __launch_bounds__(256, 2)
void g1(const unsigned short* __restrict__ fb, const unsigned short* __restrict__ agg,
        const unsigned short* __restrict__ w1T, unsigned short* __restrict__ h1) {
    __shared__ unsigned short W[128][264];   // 264: dword stride 132 -> 8-way uniform bank spread
    const int t = threadIdx.x, wave = t >> 6, lane = t & 63;
    const int m16 = lane & 15, quad = lane >> 4;
    const int row0 = blockIdx.x * 128;
    const int n0 = wave * 32;

    // Stage w1T (128x256 bf16 = 64 KB) into LDS. 256 thr x 16 iters x 16 B.
#pragma unroll
    for (int i = 0; i < 16; ++i) {
        int e = i * 2048 + t * 8;
        int n = e >> 8, k = e & 255;
        *(u16x8*)(&W[n][k]) = *(const u16x8*)(w1T + e);
    }
    __syncthreads();

    bf16x8 A[2][2][8];   // [pingpong][row-tile][kc]

    auto load_chunk = [&](int c, bf16x8 (*Ad)[8]) {
        const int r0 = row0 + c * 32;
#pragma unroll
        for (int mt = 0; mt < 2; ++mt) {
            int grow = r0 + mt * 16 + m16;
            bool ok = grow < N_NODES;
            const unsigned short* pf = fb + (long)grow * 128 + quad * 8;
            const unsigned short* pa = agg + (long)grow * 128 + quad * 8;
            bf16x8 z = {};
#pragma unroll
            for (int kc = 0; kc < 4; ++kc) Ad[mt][kc] = ok ? *(const bf16x8*)(pf + kc * 32) : z;
#pragma unroll
            for (int kc = 0; kc < 4; ++kc) Ad[mt][4 + kc] = ok ? *(const bf16x8*)(pa + kc * 32) : z;
        }
    };

    load_chunk(0, A[0]);

#pragma unroll
    for (int c = 0; c < 4; ++c) {
        if (c < 3) load_chunk(c + 1, A[(c + 1) & 1]);   // prefetch next chunk
        bf16x8 (*Ac)[8] = A[c & 1];
        f32x4 acc[2][2] = {};
#pragma unroll
        for (int kc = 0; kc < 8; ++kc) {
            bf16x8 b0 = *(const bf16x8*)(&W[n0 + m16][kc * 32 + quad * 8]);
            bf16x8 b1 = *(const bf16x8*)(&W[n0 + 16 + m16][kc * 32 + quad * 8]);
            acc[0][0] = __builtin_amdgcn_mfma_f32_16x16x32_bf16(Ac[0][kc], b0, acc[0][0], 0, 0, 0);
            acc[1][0] = __builtin_amdgcn_mfma_f32_16x16x32_bf16(Ac[1][kc], b0, acc[1][0], 0, 0, 0);
            acc[0][1] = __builtin_amdgcn_mfma_f32_16x16x32_bf16(Ac[0][kc], b1, acc[0][1], 0, 0, 0);
            acc[1][1] = __builtin_amdgcn_mfma_f32_16x16x32_bf16(Ac[1][kc], b1, acc[1][1], 0, 0, 0);
        }
        // C layout: row = quad*4 + reg, col = nt*16 + m16 (within this wave's 32-col slice)
        const int r0 = row0 + c * 32;
#pragma unroll
        for (int mt = 0; mt < 2; ++mt)
#pragma unroll
            for (int reg = 0; reg < 4; ++reg) {
                int grow = r0 + mt * 16 + quad * 4 + reg;
                if (grow >= N_NODES) continue;
#pragma unroll
                for (int nt = 0; nt < 2; ++nt)
                    h1[grow * HDIM + n0 + nt * 16 + m16] = f2bf(acc[mt][nt][reg]);
            }
    }
}

// Layer 2 fused: 64 batch rows per 256-thread block. 128 blocks exact.
__global__ __launch_bounds__(256)
void g2_fused(const unsigned short* __restrict__ h1, const unsigned short* __restrict__ w2T,
              const int* __restrict__ nbr, const int* __restrict__ nodes,
              float* __restrict__ out) {
    __shared__ unsigned short X2[64][264];
    const int t = threadIdx.x, wave = t >> 6, lane = t & 63;
    const int m16 = lane & 15, quad = lane >> 4;
    const int b0 = blockIdx.x * 64;
    const int colb = m16 * 8;

    for (int g = 0; g < 4; ++g) {
        int Ln = wave * 16 + g * 4 + quad;
        int node = nodes[b0 + Ln];
        *(u16x8*)(&X2[Ln][colb]) = *(const u16x8*)(h1 + node * HDIM + colb);
        const int* idx = nbr + node * DEG;
        float s[8] = {0.f, 0.f, 0.f, 0.f, 0.f, 0.f, 0.f, 0.f};
#pragma unroll
        for (int d = 0; d < DEG; ++d) {
            int nb = idx[d];
            u16x8 v = *(const u16x8*)(h1 + nb * HDIM + colb);
#pragma unroll
            for (int j = 0; j < 8; ++j) s[j] += bf2f(v[j]);
        }
        u16x8 o;
#pragma unroll
        for (int j = 0; j < 8; ++j) o[j] = f2bf(s[j] * 0.0625f);
        *(u16x8*)(&X2[Ln][128 + colb]) = o;
    }
    __syncthreads();

    f32x4 acc[8] = {};
#pragma unroll
    for (int kc = 0; kc < 8; ++kc) {
        bf16x8 a = *(const bf16x8*)(&X2[wave * 16 + m16][kc * 32 + quad * 8]);
#pragma unroll
        for (int nt = 0; nt < 8; ++nt) {
            bf16x8 b = *(const bf16x8*)(w2T + (nt * 16 + m16) * 256 + kc * 32 + quad * 8);
            acc[nt] = __builtin_amdgcn_mfma_f32_16x16x32_bf16(a, b, acc[nt], 0, 0, 0);
        }
    }

#pragma unroll
    for (int nt = 0; nt < 8; ++nt)
#pragma unroll
        for (int reg = 0; reg < 4; ++reg) {
            int row = b0 + wave * 16 + quad * 4 + reg;
            out[row * 128 + nt * 16 + m16] = acc[nt][reg];
        }
}

extern "C" void kernel_launch(void* const* d_in, const int* in_sizes, int n_in,
                              void* d_out, int out_size, void* d_ws, size_t ws_size,
                              hipStream_t stream) {
    const float* feat  = (const float*)d_in[0];
    const float* w1    = (const float*)d_in[1];
    const float* w2    = (const float*)d_in[2];
    const int*   nbr   = (const int*)d_in[3];
    const int*   nodes = (const int*)d_in[4];
    float* out = (float*)d_out;

    char* ws = (char*)d_ws;
    unsigned short* fb  = (unsigned short*)ws;                       // N*128 bf16 = 25.6 MB
    unsigned char*  f8  = (unsigned char*)(ws + 25600000);           // N*128 fp8  = 12.8 MB
    unsigned short* agg = (unsigned short*)(ws + 38400000);          // N*128 bf16 = 25.6 MB
    unsigned short* h1  = (unsigned short*)(ws + 64000000);          // N*128 bf16 = 25.6 MB
    unsigned short* w1T = (unsigned short*)(ws + 89600000);          // 64 KB
    unsigned short* w2T = (unsigned short*)(ws + 89665536);          // 64 KB

    prep<<<6266, 256, 0, stream>>>(feat, w1, w2, fb, f8, w1T, w2T);
    k1_agg<<<6250, 256, 0, stream>>>(f8, nbr, agg);
    g1<<<(N_NODES + 127) / 128, 256, 0, stream>>>(fb, agg, w1T, h1);
    g2_fused<<<B_NODES / 64, 256, 0, stream>>>(h1, w2T, nbr, nodes, out);
}